// Round 4
// baseline (4818.893 us; speedup 1.0000x reference)
//
#include <hip/hip_runtime.h>

// Problem dims (fixed by reference)
#define B_  256
#define L_  64
#define DI_ 2048
#define T_  32
#define DT_ 512
#define U_  512
#define A_  512
#define N3U 1536   // 3*U

typedef short short8 __attribute__((ext_vector_type(8)));   // 8 bf16 = 4 VGPRs
typedef float floatx4 __attribute__((ext_vector_type(4)));  // mfma acc
typedef unsigned short ushort4v __attribute__((ext_vector_type(4)));
typedef _Float16 h2v __attribute__((ext_vector_type(2)));
typedef _Float16 h8v __attribute__((ext_vector_type(8)));

// fp32 -> bf16 round-to-nearest-even (MFMA input path)
__device__ __forceinline__ unsigned short f2bf(float f) {
  unsigned int u = __float_as_uint(f);
  u += 0x7fffu + ((u >> 16) & 1u);
  return (unsigned short)(u >> 16);
}
// fp32 -> fp16 (RNE) bit pattern
__device__ __forceinline__ unsigned short f2h(float f) {
  union { _Float16 h; unsigned short u; } x;
  x.h = (_Float16)f;
  return x.u;
}
__device__ __forceinline__ float fast_tanh(float x) {
  x = fminf(fmaxf(x, -15.f), 15.f);
  float e = __expf(2.f * x);
  return (e - 1.f) / (e + 1.f);
}
// v_dot2_f32_f16 on packed pairs held as uint
__device__ __forceinline__ float dot2u(unsigned int w, unsigned int h, float c) {
  union { unsigned int u; h2v v; } a, b;
  a.u = w; b.u = h;
  return __builtin_amdgcn_fdot2(a.v, b.v, c, false);
}

// ---------------------------------------------------------------------------
// MFMA GEMM with fused A-conversion:
//   C[M,N] = A[M,K](fp32) @ Bt[N,K](bf16)^T (+bias)
// out_mode: 0 = fp32 row-major, 1 = f16 row-major,
//           2 = f16 in imgW8 layout [b][l>>3][col][l&7] (requires N==1536,
//               M = batch*64; acc's 4 regs = 4 consecutive l's -> 8B store).
// 128x128 tile, BK=32, 256 threads = 4 waves, each wave 64x64 sub-tile.
// ---------------------------------------------------------------------------
__global__ __launch_bounds__(256) void gemm_a32_bt16_mfma(
    const float* __restrict__ A, const unsigned short* __restrict__ Bt,
    const float* __restrict__ bias, void* __restrict__ Cout,
    int M, int N, int K, int out_mode) {
  __shared__ unsigned short As[128][40];
  __shared__ unsigned short Bs[128][40];
  const int tid  = threadIdx.x;
  const int wave = tid >> 6;
  const int lane = tid & 63;
  const int quad = lane >> 4;
  const int lr   = lane & 15;
  const int wrow = (wave >> 1) * 64;
  const int wcol = (wave & 1) * 64;
  const size_t bm = (size_t)blockIdx.y * 128;
  const size_t bn = (size_t)blockIdx.x * 128;

  const int sr = tid >> 2;          // staging row 0..63
  const int sc = (tid & 3) * 8;     // staging col (ushorts) 0,8,16,24

  floatx4 acc[4][4] = {};

  for (int k0 = 0; k0 < K; k0 += 32) {
#pragma unroll
    for (int it = 0; it < 2; ++it) {
      const int row = sr + it * 64;
      const float* ap = A + (bm + row) * (size_t)K + k0 + sc;
      float4 a0 = *(const float4*)(ap);
      float4 a1 = *(const float4*)(ap + 4);
      short8 pk;
      pk[0] = (short)f2bf(a0.x); pk[1] = (short)f2bf(a0.y);
      pk[2] = (short)f2bf(a0.z); pk[3] = (short)f2bf(a0.w);
      pk[4] = (short)f2bf(a1.x); pk[5] = (short)f2bf(a1.y);
      pk[6] = (short)f2bf(a1.z); pk[7] = (short)f2bf(a1.w);
      *(short8*)&As[row][sc] = pk;
      *(float4*)&Bs[row][sc] = *(const float4*)(Bt + (bn + row) * (size_t)K + k0 + sc);
    }
    __syncthreads();
    short8 af[4], bf[4];
#pragma unroll
    for (int mi = 0; mi < 4; ++mi) af[mi] = *(const short8*)&As[wrow + mi * 16 + lr][quad * 8];
#pragma unroll
    for (int ni = 0; ni < 4; ++ni) bf[ni] = *(const short8*)&Bs[wcol + ni * 16 + lr][quad * 8];
#pragma unroll
    for (int mi = 0; mi < 4; ++mi)
#pragma unroll
      for (int ni = 0; ni < 4; ++ni)
        acc[mi][ni] = __builtin_amdgcn_mfma_f32_16x16x32_bf16(af[mi], bf[ni], acc[mi][ni], 0, 0, 0);
    __syncthreads();
  }

  float* outf = (float*)Cout;
  unsigned short* outb = (unsigned short*)Cout;
#pragma unroll
  for (int mi = 0; mi < 4; ++mi) {
#pragma unroll
    for (int ni = 0; ni < 4; ++ni) {
      const size_t row0 = bm + wrow + mi * 16 + quad * 4;
      const size_t col  = bn + wcol + ni * 16 + lr;
      const float bsum = bias ? bias[col] : 0.f;
      if (out_mode == 2) {
        // imgW8 layout: [b][j][col][i], b=row/64, j=(row%64)>>3, i=(row%64)&7
        const size_t bidx = row0 >> 6;
        const int l0 = (int)(row0 & 63);
        const int j = l0 >> 3, i0 = l0 & 7;      // i0 in {0,4}: 4 regs contiguous
        ushort4v pk;
#pragma unroll
        for (int reg = 0; reg < 4; ++reg) pk[reg] = f2h(acc[mi][ni][reg] + bsum);
        *(ushort4v*)(outb + (((bidx * 8 + j) * 1536 + col) << 3) + i0) = pk;
      } else {
#pragma unroll
        for (int reg = 0; reg < 4; ++reg) {
          const float v = acc[mi][ni][reg] + bsum;
          if (out_mode == 1) outb[(row0 + reg) * (size_t)N + col] = f2h(v);
          else               outf[(row0 + reg) * (size_t)N + col] = v;
        }
      }
    }
  }
}

// ---------------------------------------------------------------------------
// small helpers
// ---------------------------------------------------------------------------
// in[K,N] fp32 -> out[N,K] bf16 (tiled transpose). K%32==0, N%32==0.
__global__ __launch_bounds__(256) void transpose_f32_bf16(
    const float* __restrict__ in, unsigned short* __restrict__ outp, int K, int N) {
  __shared__ unsigned short tile[32][33];
  const int tid = threadIdx.x;
  const int tx = tid & 31, ty = tid >> 5;  // ty 0..7
  const int k0 = blockIdx.y * 32, n0 = blockIdx.x * 32;
#pragma unroll
  for (int i = 0; i < 4; ++i) {
    const int kk = ty + i * 8;
    tile[tx][kk] = f2bf(in[(size_t)(k0 + kk) * N + n0 + tx]);
  }
  __syncthreads();
#pragma unroll
  for (int i = 0; i < 4; ++i) {
    const int nn = ty + i * 8;
    outp[(size_t)(n0 + nn) * K + k0 + tx] = tile[nn][tx];
  }
}

// bcat[2048] = [att_hid_bias | rec_bias]
__global__ void build_bcat(const float* __restrict__ ahb,
                           const float* __restrict__ rb,
                           float* __restrict__ bcat) {
  int i = blockIdx.x * 256 + threadIdx.x;
  if (i < A_) bcat[i] = ahb[i];
  else if (i < A_ + N3U) bcat[i] = rb[i - A_];
}

// Wcat16[k8][n][i] = W[k8*8+i][n] f16, W = [att_hid_k | rec_kern] cols n=0..2047.
__global__ __launch_bounds__(256) void build_wcat16(
    const float* __restrict__ ahk,   // [512,512]
    const float* __restrict__ rk,    // [512,1536]
    unsigned short* __restrict__ w8) {
  const int n  = blockIdx.x * 256 + threadIdx.x;  // 0..2047
  const int k8 = blockIdx.y;                       // 0..63
  short8 pk;
#pragma unroll
  for (int i = 0; i < 8; ++i) {
    const int k = k8 * 8 + i;
    const float v = (n < 512) ? ahk[(size_t)k * 512 + n]
                              : rk[(size_t)k * 1536 + (n - 512)];
    pk[i] = (short)f2h(v);
  }
  *(short8*)(w8 + ((size_t)(k8 * 2048 + n)) * 8) = pk;
}

// ---------------------------------------------------------------------------
// Batch-parallel persistent recurrence, v3: block b owns batch b, 1024 threads
// (16 waves/CU = 2x the latency hiding of v2). All hot math uses
// v_dot2_f32_f16 on f16 data; h-slices live in REGISTERS (broadcast LDS reads
// only once per step); GEMV is k-sliced across waves with an LDS partial
// reduction (partials = 64 KB dynamic LDS).
// ---------------------------------------------------------------------------
__global__ __launch_bounds__(1024) void recurrence_v3(
    const unsigned short* __restrict__ img_proj16,  // [B,L,A] f16
    const unsigned short* __restrict__ imgW16,      // [B][8][3U][8] f16
    const float* __restrict__ text_proj,            // [B,T,3U] fp32
    const unsigned short* __restrict__ wcat16,      // [64][2048][8] f16
    const float* __restrict__ bcat,                 // [2048]
    const float* __restrict__ vk,                   // [A]
    float* __restrict__ out) {                      // [B,T,U]
  extern __shared__ __align__(16) char smem_dyn[];
  float* partials = (float*)smem_dyn;               // [8][2048] f32 = 64 KB

  __shared__ __align__(16) float hm_s[2048];        // [hproj | mi]
  __shared__ __align__(16) unsigned short h16[U_];  // h as f16
  __shared__ __align__(16) float sc[L_];
  __shared__ __align__(16) unsigned int aw2[32];    // packed f16 pairs of aw
  __shared__ __align__(16) float pb[2][3][512];     // phase-B partials

  const int b    = blockIdx.x;
  const int tid  = threadIdx.x;
  const int lane = tid & 63;
  const int wave = tid >> 6;   // 0..15

  // GEMV slice constants: wave w -> k-slice ks = w>>1 (64 k's), n-half w&1
  const int ks    = wave >> 1;
  const int nbase = (wave & 1) << 10;
  const unsigned short* wp =
      wcat16 + ((size_t)(ks * 8) * 2048 + nbase + lane) * 8;

  // init
  if (tid < U_) h16[tid] = 0;
  float h_prev = 0.f;

  // hoisted invariants
  float vvv[8];
  {
    float4 v0 = *(const float4*)(vk + lane * 8);
    float4 v1 = *(const float4*)(vk + lane * 8 + 4);
    vvv[0]=v0.x; vvv[1]=v0.y; vvv[2]=v0.z; vvv[3]=v0.w;
    vvv[4]=v1.x; vvv[5]=v1.y; vvv[6]=v1.z; vvv[7]=v1.w;
  }
  const float bcv0 = bcat[tid];
  const float bcv1 = bcat[tid + 1024];

  __syncthreads();

  for (int t = 0; t < T_; ++t) {
    // ---- phase 0: GEMV partials; thread covers n = nbase + j*64 + lane ----
    {
      float acc[16];
#pragma unroll
      for (int j = 0; j < 16; ++j) acc[j] = 0.f;
#pragma unroll
      for (int cc = 0; cc < 2; ++cc) {
        uint4 hv[4];
#pragma unroll
        for (int c = 0; c < 4; ++c)
          hv[c] = *(const uint4*)&h16[ks * 64 + cc * 32 + c * 8];  // broadcast
#pragma unroll
        for (int j = 0; j < 16; ++j) {
#pragma unroll
          for (int c = 0; c < 4; ++c) {
            uint4 wv = *(const uint4*)(wp + ((size_t)(cc * 4 + c) * 2048 + j * 64) * 8);
            acc[j] = dot2u(wv.x, hv[c].x, acc[j]);
            acc[j] = dot2u(wv.y, hv[c].y, acc[j]);
            acc[j] = dot2u(wv.z, hv[c].z, acc[j]);
            acc[j] = dot2u(wv.w, hv[c].w, acc[j]);
          }
        }
      }
#pragma unroll
      for (int j = 0; j < 16; ++j)
        partials[ks * 2048 + nbase + j * 64 + lane] = acc[j];
    }
    __syncthreads();

    // ---- reduce partials -> hm_s (k-slices ascending = original k order) ----
    {
      float r0 = bcv0, r1 = bcv1;
#pragma unroll
      for (int s2 = 0; s2 < 8; ++s2) {
        r0 += partials[s2 * 2048 + tid];
        r1 += partials[s2 * 2048 + tid + 1024];
      }
      hm_s[tid] = r0;
      hm_s[tid + 1024] = r1;
    }
    __syncthreads();

    // ---- phase A: attention scores; wave w -> l = w, w+16, w+32, w+48 ----
    {
      float hpv[8];
      float4 h0 = *(const float4*)&hm_s[lane * 8];
      float4 h1 = *(const float4*)&hm_s[lane * 8 + 4];
      hpv[0]=h0.x; hpv[1]=h0.y; hpv[2]=h0.z; hpv[3]=h0.w;
      hpv[4]=h1.x; hpv[5]=h1.y; hpv[6]=h1.z; hpv[7]=h1.w;
#pragma unroll
      for (int i = 0; i < 4; ++i) {
        const int l = wave + i * 16;
        const unsigned short* ip = img_proj16 + ((size_t)b * L_ + l) * A_ + lane * 8;
        h8v v8 = *(const h8v*)ip;
        float s = 0.f;
#pragma unroll
        for (int j = 0; j < 8; ++j)
          s += fast_tanh((float)v8[j] + hpv[j]) * vvv[j];
#pragma unroll
        for (int off = 32; off; off >>= 1) s += __shfl_down(s, off);
        if (lane == 0) sc[l] = s;
      }
    }
    __syncthreads();

    // ---- softmax over 64 regions (wave 0), pack aw to f16 pairs ----
    if (tid < 64) {
      float x = sc[tid];
      float m = x;
#pragma unroll
      for (int off = 32; off; off >>= 1) m = fmaxf(m, __shfl_xor(m, off));
      float e = __expf(x - m);
      float ssum = e;
#pragma unroll
      for (int off = 32; off; off >>= 1) ssum += __shfl_xor(ssum, off);
      const float a = e / ssum;
      const float a0 = __shfl(a, (tid & 31) * 2);
      const float a1 = __shfl(a, (tid & 31) * 2 + 1);
      if (tid < 32) {
        aw2[tid] = (unsigned int)f2h(a0) | ((unsigned int)f2h(a1) << 16);
      }
    }
    __syncthreads();

    // ---- phase B: ctx combine; thread (u, half) does l-blocks half*4..+4 ----
    {
      const int u = tid & 511;
      const int hf = tid >> 9;
      const unsigned short* iwb = imgW16 + (size_t)b * (8 * N3U * 8)
                                 + (size_t)(hf * 4) * (N3U * 8) + (size_t)u * 8;
      float s0 = 0.f, s1 = 0.f, s2 = 0.f;
#pragma unroll
      for (int jj = 0; jj < 4; ++jj) {
        uint4 ap = *(const uint4*)&aw2[(hf * 4 + jj) * 4];
        const unsigned short* pj = iwb + (size_t)jj * (N3U * 8);
        uint4 w0 = *(const uint4*)(pj);
        uint4 w1 = *(const uint4*)(pj + 512 * 8);
        uint4 w2 = *(const uint4*)(pj + 1024 * 8);
        s0 = dot2u(w0.x, ap.x, s0); s0 = dot2u(w0.y, ap.y, s0);
        s0 = dot2u(w0.z, ap.z, s0); s0 = dot2u(w0.w, ap.w, s0);
        s1 = dot2u(w1.x, ap.x, s1); s1 = dot2u(w1.y, ap.y, s1);
        s1 = dot2u(w1.z, ap.z, s1); s1 = dot2u(w1.w, ap.w, s1);
        s2 = dot2u(w2.x, ap.x, s2); s2 = dot2u(w2.y, ap.y, s2);
        s2 = dot2u(w2.z, ap.z, s2); s2 = dot2u(w2.w, ap.w, s2);
      }
      pb[hf][0][u] = s0;
      pb[hf][1][u] = s1;
      pb[hf][2][u] = s2;
    }
    __syncthreads();

    // ---- gates (threads 0..511) ----
    if (tid < 512) {
      const int u = tid;
      const float* tp = text_proj + ((size_t)b * T_ + t) * N3U;
      const float s0 = pb[0][0][u] + pb[1][0][u];
      const float s1 = pb[0][1][u] + pb[1][1][u];
      const float s2 = pb[0][2][u] + pb[1][2][u];
      const float xz = s0 + tp[u]        + hm_s[512 + u];
      const float xr = s1 + tp[512 + u]  + hm_s[1024 + u];
      const float xh = s2 + tp[1024 + u];
      const float rh = hm_s[1536 + u];
      const float z  = 1.f / (1.f + __expf(-xz));
      const float r  = 1.f / (1.f + __expf(-xr));
      const float hh = fast_tanh(xh + r * rh);
      const float hn = z * h_prev + (1.f - z) * hh;
      h_prev = hn;
      h16[u] = f2h(hn);
      out[((size_t)b * T_ + t) * U_ + u] = hn;
    }
    __syncthreads();
  }
}

// ---------------------------------------------------------------------------
// launch
// ---------------------------------------------------------------------------
extern "C" void kernel_launch(void* const* d_in, const int* in_sizes, int n_in,
                              void* d_out, int out_size, void* d_ws, size_t ws_size,
                              hipStream_t stream) {
  const float* img        = (const float*)d_in[0];   // [B,L,DI]
  const float* text       = (const float*)d_in[1];   // [B,T,DT]
  const float* kern       = (const float*)d_in[2];   // [DT+DI, 3U]
  const float* input_bias = (const float*)d_in[3];   // [3U]
  const float* rec_kern   = (const float*)d_in[4];   // [U,3U]
  const float* rec_bias   = (const float*)d_in[5];   // [3U]
  const float* att_img_k  = (const float*)d_in[6];   // [DI,A]
  const float* att_img_b  = (const float*)d_in[7];   // [A]
  const float* att_hid_k  = (const float*)d_in[8];   // [U,A]
  const float* att_hid_b  = (const float*)d_in[9];   // [A]
  const float* att_v_k    = (const float*)d_in[10];  // [A,1]
  // d_in[11] = att_v_bias — cancels in softmax.
  float* out = (float*)d_out;

  // workspace layout (bytes, 256-aligned). NO ALIASING.
  char* ws = (char*)d_ws;
  size_t off = 0;
  auto alloc = [&](size_t bytes) { char* p = ws + off; off += (bytes + 255) & ~(size_t)255; return p; };
  unsigned short* img_proj = (unsigned short*)alloc((size_t)B_*L_*A_*2);   // 16.8 MB f16
  unsigned short* imgW16   = (unsigned short*)alloc((size_t)B_*L_*N3U*2);  // 50.3 MB f16 [b][j][n][i]
  float*          text_proj= (float*)         alloc((size_t)B_*T_*N3U*4);  // 50.3 MB fp32
  unsigned short* wt1      = (unsigned short*)alloc((size_t)A_*DI_*2);     // att_img_k^T bf16
  unsigned short* wt2      = (unsigned short*)alloc((size_t)N3U*DI_*2);    // kern[DT:]^T bf16
  unsigned short* wt3      = (unsigned short*)alloc((size_t)N3U*DT_*2);    // kern[:DT]^T bf16
  unsigned short* wcat16   = (unsigned short*)alloc((size_t)64*2048*8*2);  // 2 MB f16
  float*          bcat     = (float*)         alloc(2048*4);

  dim3 blk(256);

  // allow 64 KB dynamic LDS for the recurrence (host-side attr, graph-safe)
  static bool attr_set = false;
  if (!attr_set) {
    (void)hipFuncSetAttribute((const void*)recurrence_v3,
                              hipFuncAttributeMaxDynamicSharedMemorySize, 65536);
    attr_set = true;
  }

  // one-time weight transforms
  transpose_f32_bf16<<<dim3(A_/32, DI_/32), blk, 0, stream>>>(att_img_k, wt1, DI_, A_);
  transpose_f32_bf16<<<dim3(N3U/32, DI_/32), blk, 0, stream>>>(kern + (size_t)DT_*N3U, wt2, DI_, N3U);
  transpose_f32_bf16<<<dim3(N3U/32, DT_/32), blk, 0, stream>>>(kern, wt3, DT_, N3U);
  build_wcat16<<<dim3(2048/256, 64), blk, 0, stream>>>(att_hid_k, rec_kern, wcat16);
  build_bcat<<<dim3(8), blk, 0, stream>>>(att_hid_b, rec_bias, bcat);

  // big GEMMs on MFMA (A operand converted fp32->bf16 during staging)
  gemm_a32_bt16_mfma<<<dim3(A_/128, (B_*L_)/128), blk, 0, stream>>>(
      img, wt1, att_img_b, img_proj, B_*L_, A_, DI_, 1);
  gemm_a32_bt16_mfma<<<dim3(N3U/128, (B_*L_)/128), blk, 0, stream>>>(
      img, wt2, nullptr, imgW16, B_*L_, N3U, DI_, 2);     // direct imgW8 layout
  gemm_a32_bt16_mfma<<<dim3(N3U/128, (B_*T_)/128), blk, 0, stream>>>(
      text, wt3, input_bias, text_proj, B_*T_, N3U, DT_, 0);

  // entire 32-step recurrence: ONE plain launch, block b = batch b, no syncs
  recurrence_v3<<<dim3(B_), dim3(1024), 65536, stream>>>(
      img_proj, imgW16, text_proj, wcat16, bcat, att_v_k, out);
}

// Round 6
// 1570.706 us; speedup vs baseline: 3.0680x; 3.0680x over previous
//
#include <hip/hip_runtime.h>

// Problem dims (fixed by reference)
#define B_  256
#define L_  64
#define DI_ 2048
#define T_  32
#define DT_ 512
#define U_  512
#define A_  512
#define N3U 1536   // 3*U

typedef short short8 __attribute__((ext_vector_type(8)));   // 8 bf16 = 4 VGPRs
typedef float floatx4 __attribute__((ext_vector_type(4)));  // mfma acc
typedef unsigned short ushort4v __attribute__((ext_vector_type(4)));
typedef _Float16 h2v __attribute__((ext_vector_type(2)));
typedef _Float16 h8v __attribute__((ext_vector_type(8)));

// fp32 -> bf16 round-to-nearest-even (MFMA input path)
__device__ __forceinline__ unsigned short f2bf(float f) {
  unsigned int u = __float_as_uint(f);
  u += 0x7fffu + ((u >> 16) & 1u);
  return (unsigned short)(u >> 16);
}
// fp32 -> fp16 (RNE) bit pattern
__device__ __forceinline__ unsigned short f2h(float f) {
  union { _Float16 h; unsigned short u; } x;
  x.h = (_Float16)f;
  return x.u;
}
__device__ __forceinline__ float fast_tanh(float x) {
  x = fminf(fmaxf(x, -15.f), 15.f);
  float e = __expf(2.f * x);
  return (e - 1.f) / (e + 1.f);
}
// v_dot2_f32_f16 on packed pairs held as uint
__device__ __forceinline__ float dot2u(unsigned int w, unsigned int h, float c) {
  union { unsigned int u; h2v v; } a, b;
  a.u = w; b.u = h;
  return __builtin_amdgcn_fdot2(a.v, b.v, c, false);
}

// ---------------------------------------------------------------------------
// MFMA GEMM with fused A-conversion:
//   C[M,N] = A[M,K](fp32) @ Bt[N,K](bf16)^T (+bias)
// out_mode: 0 = fp32 row-major, 1 = f16 row-major,
//           2 = f16 in imgW8 layout [b][l>>3][col][l&7] (requires N==1536,
//               M = batch*64; acc's 4 regs = 4 consecutive l's -> 8B store).
// 128x128 tile, BK=32, 256 threads = 4 waves, each wave 64x64 sub-tile.
// ---------------------------------------------------------------------------
__global__ __launch_bounds__(256) void gemm_a32_bt16_mfma(
    const float* __restrict__ A, const unsigned short* __restrict__ Bt,
    const float* __restrict__ bias, void* __restrict__ Cout,
    int M, int N, int K, int out_mode) {
  __shared__ unsigned short As[128][40];
  __shared__ unsigned short Bs[128][40];
  const int tid  = threadIdx.x;
  const int wave = tid >> 6;
  const int lane = tid & 63;
  const int quad = lane >> 4;
  const int lr   = lane & 15;
  const int wrow = (wave >> 1) * 64;
  const int wcol = (wave & 1) * 64;
  const size_t bm = (size_t)blockIdx.y * 128;
  const size_t bn = (size_t)blockIdx.x * 128;

  const int sr = tid >> 2;          // staging row 0..63
  const int sc = (tid & 3) * 8;     // staging col (ushorts) 0,8,16,24

  floatx4 acc[4][4] = {};

  for (int k0 = 0; k0 < K; k0 += 32) {
#pragma unroll
    for (int it = 0; it < 2; ++it) {
      const int row = sr + it * 64;
      const float* ap = A + (bm + row) * (size_t)K + k0 + sc;
      float4 a0 = *(const float4*)(ap);
      float4 a1 = *(const float4*)(ap + 4);
      short8 pk;
      pk[0] = (short)f2bf(a0.x); pk[1] = (short)f2bf(a0.y);
      pk[2] = (short)f2bf(a0.z); pk[3] = (short)f2bf(a0.w);
      pk[4] = (short)f2bf(a1.x); pk[5] = (short)f2bf(a1.y);
      pk[6] = (short)f2bf(a1.z); pk[7] = (short)f2bf(a1.w);
      *(short8*)&As[row][sc] = pk;
      *(float4*)&Bs[row][sc] = *(const float4*)(Bt + (bn + row) * (size_t)K + k0 + sc);
    }
    __syncthreads();
    short8 af[4], bf[4];
#pragma unroll
    for (int mi = 0; mi < 4; ++mi) af[mi] = *(const short8*)&As[wrow + mi * 16 + lr][quad * 8];
#pragma unroll
    for (int ni = 0; ni < 4; ++ni) bf[ni] = *(const short8*)&Bs[wcol + ni * 16 + lr][quad * 8];
#pragma unroll
    for (int mi = 0; mi < 4; ++mi)
#pragma unroll
      for (int ni = 0; ni < 4; ++ni)
        acc[mi][ni] = __builtin_amdgcn_mfma_f32_16x16x32_bf16(af[mi], bf[ni], acc[mi][ni], 0, 0, 0);
    __syncthreads();
  }

  float* outf = (float*)Cout;
  unsigned short* outb = (unsigned short*)Cout;
#pragma unroll
  for (int mi = 0; mi < 4; ++mi) {
#pragma unroll
    for (int ni = 0; ni < 4; ++ni) {
      const size_t row0 = bm + wrow + mi * 16 + quad * 4;
      const size_t col  = bn + wcol + ni * 16 + lr;
      const float bsum = bias ? bias[col] : 0.f;
      if (out_mode == 2) {
        // imgW8 layout: [b][j][col][i], b=row/64, j=(row%64)>>3, i=(row%64)&7
        const size_t bidx = row0 >> 6;
        const int l0 = (int)(row0 & 63);
        const int j = l0 >> 3, i0 = l0 & 7;      // i0 in {0,4}: 4 regs contiguous
        ushort4v pk;
#pragma unroll
        for (int reg = 0; reg < 4; ++reg) pk[reg] = f2h(acc[mi][ni][reg] + bsum);
        *(ushort4v*)(outb + (((bidx * 8 + j) * 1536 + col) << 3) + i0) = pk;
      } else {
#pragma unroll
        for (int reg = 0; reg < 4; ++reg) {
          const float v = acc[mi][ni][reg] + bsum;
          if (out_mode == 1) outb[(row0 + reg) * (size_t)N + col] = f2h(v);
          else               outf[(row0 + reg) * (size_t)N + col] = v;
        }
      }
    }
  }
}

// ---------------------------------------------------------------------------
// small helpers
// ---------------------------------------------------------------------------
// in[K,N] fp32 -> out[N,K] bf16 (tiled transpose). K%32==0, N%32==0.
__global__ __launch_bounds__(256) void transpose_f32_bf16(
    const float* __restrict__ in, unsigned short* __restrict__ outp, int K, int N) {
  __shared__ unsigned short tile[32][33];
  const int tid = threadIdx.x;
  const int tx = tid & 31, ty = tid >> 5;  // ty 0..7
  const int k0 = blockIdx.y * 32, n0 = blockIdx.x * 32;
#pragma unroll
  for (int i = 0; i < 4; ++i) {
    const int kk = ty + i * 8;
    tile[tx][kk] = f2bf(in[(size_t)(k0 + kk) * N + n0 + tx]);
  }
  __syncthreads();
#pragma unroll
  for (int i = 0; i < 4; ++i) {
    const int nn = ty + i * 8;
    outp[(size_t)(n0 + nn) * K + k0 + tx] = tile[nn][tx];
  }
}

// bcat[2048] = [att_hid_bias | rec_bias]
__global__ void build_bcat(const float* __restrict__ ahb,
                           const float* __restrict__ rb,
                           float* __restrict__ bcat) {
  int i = blockIdx.x * 256 + threadIdx.x;
  if (i < A_) bcat[i] = ahb[i];
  else if (i < A_ + N3U) bcat[i] = rb[i - A_];
}

// Wcat16[k8][n][i] = W[k8*8+i][n] f16, W = [att_hid_k | rec_kern] cols n=0..2047.
__global__ __launch_bounds__(256) void build_wcat16(
    const float* __restrict__ ahk,   // [512,512]
    const float* __restrict__ rk,    // [512,1536]
    unsigned short* __restrict__ w8) {
  const int n  = blockIdx.x * 256 + threadIdx.x;  // 0..2047
  const int k8 = blockIdx.y;                       // 0..63
  short8 pk;
#pragma unroll
  for (int i = 0; i < 8; ++i) {
    const int k = k8 * 8 + i;
    const float v = (n < 512) ? ahk[(size_t)k * 512 + n]
                              : rk[(size_t)k * 1536 + (n - 512)];
    pk[i] = (short)f2h(v);
  }
  *(short8*)(w8 + ((size_t)(k8 * 2048 + n)) * 8) = pk;
}

// ---------------------------------------------------------------------------
// Batch-parallel persistent recurrence, v5: block b owns batch b, 1024 threads
// (4 waves/SIMD pinned via launch_bounds -> 128 VGPR budget, no spills;
// v3's 8.6 GB FETCH / 605 MB WRITE was scratch spill traffic at VGPR=64).
// v2's proven whole-block sequential k8 GEMV sweep (L2-kind) + f16/v_dot2.
// Per step:
//   phase 0: GEMV hm = h @ Wcat + bcat; thread owns n = {tid, tid+1024};
//            per k8: 1 LDS b128 broadcast (h pairs) + 2 global dwordx4 +
//            8 fdot2. Block sweeps wcat16 front-to-back (32 KB windows).
//   phase A: scores; wave w -> l = w, w+16, w+32, w+48
//   softmax (first 64 threads) -> packed f16 pairs aw2
//   phase B: ctx combine via imgW16, split over thread-halves, LDS reduce
//   gates (threads 0..511)
// ---------------------------------------------------------------------------
__global__ __launch_bounds__(1024, 4) void recurrence_v5(
    const unsigned short* __restrict__ img_proj16,  // [B,L,A] f16
    const unsigned short* __restrict__ imgW16,      // [B][8][3U][8] f16
    const float* __restrict__ text_proj,            // [B,T,3U] fp32
    const unsigned short* __restrict__ wcat16,      // [64][2048][8] f16
    const float* __restrict__ bcat,                 // [2048]
    const float* __restrict__ vk,                   // [A]
    float* __restrict__ out) {                      // [B,T,U]
  __shared__ __align__(16) float hm_s[2048];        // [hproj | mi]
  __shared__ __align__(16) unsigned short h16[U_];  // h as f16
  __shared__ __align__(16) float sc[L_];
  __shared__ __align__(16) unsigned int aw2[32];    // packed f16 pairs of aw
  __shared__ __align__(16) float pb[2][3][512];     // phase-B partials

  const int b    = blockIdx.x;
  const int tid  = threadIdx.x;
  const int lane = tid & 63;
  const int wave = tid >> 6;   // 0..15

  // init
  if (tid < U_) h16[tid] = 0;
  float h_prev = 0.f;

  // hoisted invariants
  float vvv[8];
  {
    float4 v0 = *(const float4*)(vk + lane * 8);
    float4 v1 = *(const float4*)(vk + lane * 8 + 4);
    vvv[0]=v0.x; vvv[1]=v0.y; vvv[2]=v0.z; vvv[3]=v0.w;
    vvv[4]=v1.x; vvv[5]=v1.y; vvv[6]=v1.z; vvv[7]=v1.w;
  }
  const float bcv0 = bcat[tid];
  const float bcv1 = bcat[tid + 1024];

  __syncthreads();

  for (int t = 0; t < T_; ++t) {
    // ---- phase 0: GEMV; thread owns n = tid and n = tid+1024 ----
    {
      float a0 = 0.f, a1 = 0.f;
      const unsigned short* wp = wcat16 + (size_t)tid * 8;
#pragma unroll 4
      for (int k8 = 0; k8 < 64; ++k8) {
        uint4 hv = *(const uint4*)&h16[k8 * 8];          // LDS broadcast, 16B
        const unsigned short* wk = wp + (size_t)k8 * (2048 * 8);
        uint4 w0 = *(const uint4*)(wk);
        uint4 w1 = *(const uint4*)(wk + 1024 * 8);
        a0 = dot2u(w0.x, hv.x, a0); a0 = dot2u(w0.y, hv.y, a0);
        a0 = dot2u(w0.z, hv.z, a0); a0 = dot2u(w0.w, hv.w, a0);
        a1 = dot2u(w1.x, hv.x, a1); a1 = dot2u(w1.y, hv.y, a1);
        a1 = dot2u(w1.z, hv.z, a1); a1 = dot2u(w1.w, hv.w, a1);
      }
      hm_s[tid]        = a0 + bcv0;
      hm_s[tid + 1024] = a1 + bcv1;
    }
    __syncthreads();

    // ---- phase A: attention scores; wave w -> l = w, w+16, w+32, w+48 ----
    {
      float hpv[8];
      float4 h0 = *(const float4*)&hm_s[lane * 8];
      float4 h1 = *(const float4*)&hm_s[lane * 8 + 4];
      hpv[0]=h0.x; hpv[1]=h0.y; hpv[2]=h0.z; hpv[3]=h0.w;
      hpv[4]=h1.x; hpv[5]=h1.y; hpv[6]=h1.z; hpv[7]=h1.w;
#pragma unroll
      for (int i = 0; i < 4; ++i) {
        const int l = wave + i * 16;
        const unsigned short* ip = img_proj16 + ((size_t)b * L_ + l) * A_ + lane * 8;
        h8v v8 = *(const h8v*)ip;
        float s = 0.f;
#pragma unroll
        for (int j = 0; j < 8; ++j)
          s += fast_tanh((float)v8[j] + hpv[j]) * vvv[j];
#pragma unroll
        for (int off = 32; off; off >>= 1) s += __shfl_down(s, off);
        if (lane == 0) sc[l] = s;
      }
    }
    __syncthreads();

    // ---- softmax over 64 regions (wave 0), pack aw to f16 pairs ----
    if (tid < 64) {
      float x = sc[tid];
      float m = x;
#pragma unroll
      for (int off = 32; off; off >>= 1) m = fmaxf(m, __shfl_xor(m, off));
      float e = __expf(x - m);
      float ssum = e;
#pragma unroll
      for (int off = 32; off; off >>= 1) ssum += __shfl_xor(ssum, off);
      const float a = e / ssum;
      const float a0 = __shfl(a, (tid & 31) * 2);
      const float a1 = __shfl(a, (tid & 31) * 2 + 1);
      if (tid < 32) {
        aw2[tid] = (unsigned int)f2h(a0) | ((unsigned int)f2h(a1) << 16);
      }
    }
    __syncthreads();

    // ---- phase B: ctx combine; thread (u, half) does l-blocks half*4..+4 ----
    {
      const int u = tid & 511;
      const int hf = tid >> 9;
      const unsigned short* iwb = imgW16 + (size_t)b * (8 * N3U * 8)
                                 + (size_t)(hf * 4) * (N3U * 8) + (size_t)u * 8;
      float s0 = 0.f, s1 = 0.f, s2 = 0.f;
#pragma unroll
      for (int jj = 0; jj < 4; ++jj) {
        uint4 ap = *(const uint4*)&aw2[(hf * 4 + jj) * 4];
        const unsigned short* pj = iwb + (size_t)jj * (N3U * 8);
        uint4 w0 = *(const uint4*)(pj);
        uint4 w1 = *(const uint4*)(pj + 512 * 8);
        uint4 w2 = *(const uint4*)(pj + 1024 * 8);
        s0 = dot2u(w0.x, ap.x, s0); s0 = dot2u(w0.y, ap.y, s0);
        s0 = dot2u(w0.z, ap.z, s0); s0 = dot2u(w0.w, ap.w, s0);
        s1 = dot2u(w1.x, ap.x, s1); s1 = dot2u(w1.y, ap.y, s1);
        s1 = dot2u(w1.z, ap.z, s1); s1 = dot2u(w1.w, ap.w, s1);
        s2 = dot2u(w2.x, ap.x, s2); s2 = dot2u(w2.y, ap.y, s2);
        s2 = dot2u(w2.z, ap.z, s2); s2 = dot2u(w2.w, ap.w, s2);
      }
      pb[hf][0][u] = s0;
      pb[hf][1][u] = s1;
      pb[hf][2][u] = s2;
    }
    __syncthreads();

    // ---- gates (threads 0..511) ----
    if (tid < 512) {
      const int u = tid;
      const float* tp = text_proj + ((size_t)b * T_ + t) * N3U;
      const float s0 = pb[0][0][u] + pb[1][0][u];
      const float s1 = pb[0][1][u] + pb[1][1][u];
      const float s2 = pb[0][2][u] + pb[1][2][u];
      const float xz = s0 + tp[u]        + hm_s[512 + u];
      const float xr = s1 + tp[512 + u]  + hm_s[1024 + u];
      const float xh = s2 + tp[1024 + u];
      const float rh = hm_s[1536 + u];
      const float z  = 1.f / (1.f + __expf(-xz));
      const float r  = 1.f / (1.f + __expf(-xr));
      const float hh = fast_tanh(xh + r * rh);
      const float hn = z * h_prev + (1.f - z) * hh;
      h_prev = hn;
      h16[u] = f2h(hn);
      out[((size_t)b * T_ + t) * U_ + u] = hn;
    }
    __syncthreads();
  }
}

// ---------------------------------------------------------------------------
// launch
// ---------------------------------------------------------------------------
extern "C" void kernel_launch(void* const* d_in, const int* in_sizes, int n_in,
                              void* d_out, int out_size, void* d_ws, size_t ws_size,
                              hipStream_t stream) {
  const float* img        = (const float*)d_in[0];   // [B,L,DI]
  const float* text       = (const float*)d_in[1];   // [B,T,DT]
  const float* kern       = (const float*)d_in[2];   // [DT+DI, 3U]
  const float* input_bias = (const float*)d_in[3];   // [3U]
  const float* rec_kern   = (const float*)d_in[4];   // [U,3U]
  const float* rec_bias   = (const float*)d_in[5];   // [3U]
  const float* att_img_k  = (const float*)d_in[6];   // [DI,A]
  const float* att_img_b  = (const float*)d_in[7];   // [A]
  const float* att_hid_k  = (const float*)d_in[8];   // [U,A]
  const float* att_hid_b  = (const float*)d_in[9];   // [A]
  const float* att_v_k    = (const float*)d_in[10];  // [A,1]
  // d_in[11] = att_v_bias — cancels in softmax.
  float* out = (float*)d_out;

  // workspace layout (bytes, 256-aligned). NO ALIASING.
  char* ws = (char*)d_ws;
  size_t off = 0;
  auto alloc = [&](size_t bytes) { char* p = ws + off; off += (bytes + 255) & ~(size_t)255; return p; };
  unsigned short* img_proj = (unsigned short*)alloc((size_t)B_*L_*A_*2);   // 16.8 MB f16
  unsigned short* imgW16   = (unsigned short*)alloc((size_t)B_*L_*N3U*2);  // 50.3 MB f16 [b][j][n][i]
  float*          text_proj= (float*)         alloc((size_t)B_*T_*N3U*4);  // 50.3 MB fp32
  unsigned short* wt1      = (unsigned short*)alloc((size_t)A_*DI_*2);     // att_img_k^T bf16
  unsigned short* wt2      = (unsigned short*)alloc((size_t)N3U*DI_*2);    // kern[DT:]^T bf16
  unsigned short* wt3      = (unsigned short*)alloc((size_t)N3U*DT_*2);    // kern[:DT]^T bf16
  unsigned short* wcat16   = (unsigned short*)alloc((size_t)64*2048*8*2);  // 2 MB f16
  float*          bcat     = (float*)         alloc(2048*4);

  dim3 blk(256);

  // one-time weight transforms
  transpose_f32_bf16<<<dim3(A_/32, DI_/32), blk, 0, stream>>>(att_img_k, wt1, DI_, A_);
  transpose_f32_bf16<<<dim3(N3U/32, DI_/32), blk, 0, stream>>>(kern + (size_t)DT_*N3U, wt2, DI_, N3U);
  transpose_f32_bf16<<<dim3(N3U/32, DT_/32), blk, 0, stream>>>(kern, wt3, DT_, N3U);
  build_wcat16<<<dim3(2048/256, 64), blk, 0, stream>>>(att_hid_k, rec_kern, wcat16);
  build_bcat<<<dim3(8), blk, 0, stream>>>(att_hid_b, rec_bias, bcat);

  // big GEMMs on MFMA (A operand converted fp32->bf16 during staging)
  gemm_a32_bt16_mfma<<<dim3(A_/128, (B_*L_)/128), blk, 0, stream>>>(
      img, wt1, att_img_b, img_proj, B_*L_, A_, DI_, 1);
  gemm_a32_bt16_mfma<<<dim3(N3U/128, (B_*L_)/128), blk, 0, stream>>>(
      img, wt2, nullptr, imgW16, B_*L_, N3U, DI_, 2);     // direct imgW8 layout
  gemm_a32_bt16_mfma<<<dim3(N3U/128, (B_*T_)/128), blk, 0, stream>>>(
      text, wt3, input_bias, text_proj, B_*T_, N3U, DT_, 0);

  // entire 32-step recurrence: ONE plain launch, block b = batch b, no syncs
  recurrence_v5<<<dim3(B_), dim3(1024), 0, stream>>>(
      img_proj, imgW16, text_proj, wcat16, bcat, att_v_k, out);
}